// Round 3
// baseline (3552.415 us; speedup 1.0000x reference)
//
#include <hip/hip_runtime.h>
#include <hip/hip_bf16.h>

// x[N,128] f32, edge_index[2,E] int, edge_label[E,4] f32,
// weight[512,256] f32, trans_weight[4,128] f32, bias[256] f32 -> out[N,256] f32
//
// Pipeline:
//   convert_x : x -> bf16 pairs (xh), staged in d_out
//   hist_b    : per-bucket (128 nodes) edge counts, LDS-preaggregated
//   scan_b    : exclusive scan of bucket counts -> offsets + cursors
//   bin_kernel: scatter (partner, edge|local) entries into bucket segments
//   accum_b   : one block per bucket; LDS fp32 accumulators (128 nodes x 128 ch),
//               ds_add_f32 atomics; writes means + label means once
//   gemm      : 64x256 tile, K=256 main loop + rank-8 opinion epilogue (P1/P3)

#define BK 128   // nodes per bucket

__global__ void convert_x(const float2* __restrict__ x2,
                          __hip_bfloat162* __restrict__ xh, int n2)
{
    int i = blockIdx.x * 256 + threadIdx.x;
    const int stride = gridDim.x * 256;
    for (; i < n2; i += stride) {
        const float2 v = x2[i];
        __hip_bfloat162 p;
        p.x = __float2bfloat16(v.x);
        p.y = __float2bfloat16(v.y);
        xh[i] = p;
    }
}

__global__ __launch_bounds__(256) void hist_b(const int* __restrict__ eidx,
                                              int* __restrict__ cnt_r,
                                              int* __restrict__ cnt_c, int E, int nbk)
{
    __shared__ int hr[1024], hc[1024];
    const int t = threadIdx.x;
    for (int i = t; i < nbk; i += 256) { hr[i] = 0; hc[i] = 0; }
    __syncthreads();
    for (int e = blockIdx.x * 256 + t; e < E; e += gridDim.x * 256) {
        atomicAdd(&hr[((unsigned)eidx[e]) >> 7], 1);
        atomicAdd(&hc[((unsigned)eidx[E + e]) >> 7], 1);
    }
    __syncthreads();
    for (int i = t; i < nbk; i += 256) {
        if (hr[i]) atomicAdd(&cnt_r[i], hr[i]);
        if (hc[i]) atomicAdd(&cnt_c[i], hc[i]);
    }
}

// blockIdx.x = 0 -> row direction, 1 -> col direction. nbk <= 1024.
__global__ __launch_bounds__(1024) void scan_b(const int* __restrict__ cnt_r,
                                               const int* __restrict__ cnt_c,
                                               int* __restrict__ boff_r,
                                               int* __restrict__ boff_c,
                                               int* __restrict__ cur_r,
                                               int* __restrict__ cur_c, int nbk)
{
    __shared__ int sh[1024];
    const int t = threadIdx.x;
    const int* cnt = blockIdx.x ? cnt_c : cnt_r;
    int* boff = blockIdx.x ? boff_c : boff_r;
    int* cur  = blockIdx.x ? cur_c  : cur_r;
    const int v = (t < nbk) ? cnt[t] : 0;
    sh[t] = v;
    __syncthreads();
    for (int s = 1; s < 1024; s <<= 1) {
        const int tmp = (t >= s) ? sh[t - s] : 0;
        __syncthreads();
        sh[t] += tmp;
        __syncthreads();
    }
    if (t < nbk) { const int off = sh[t] - v; boff[t] = off; cur[t] = off; }
    if (t == 0) boff[nbk] = sh[1023];
}

__global__ void bin_kernel(const int* __restrict__ eidx,
                           int* __restrict__ cur_r, int* __restrict__ cur_c,
                           uint2* __restrict__ ent_r, uint2* __restrict__ ent_c, int E)
{
    const int e = blockIdx.x * 256 + threadIdx.x;
    if (e >= E) return;
    const unsigned row = (unsigned)eidx[e];
    const unsigned col = (unsigned)eidx[E + e];
    const int p = atomicAdd(&cur_r[row >> 7], 1);
    ent_r[p] = make_uint2(col, (unsigned)e | ((row & 127u) << 21));
    const int q = atomicAdd(&cur_c[col >> 7], 1);
    ent_c[q] = make_uint2(row, (unsigned)e | ((col & 127u) << 21));
}

// one block per bucket of 128 nodes; LDS accumulators + ds_add_f32
__global__ __launch_bounds__(256) void accum_b(
    const __hip_bfloat162* __restrict__ xh, const float* __restrict__ elabel,
    const uint2* __restrict__ ent, const int* __restrict__ boff,
    float* __restrict__ mean, float* __restrict__ labmean, int n)
{
    __shared__ float acc[BK * 128];
    __shared__ float lab[BK * 4];
    __shared__ float deg[BK];
    const int t = threadIdx.x;
    const int b = blockIdx.x;
    for (int i = t; i < BK * 128; i += 256) acc[i] = 0.f;
    for (int i = t; i < BK * 4; i += 256) lab[i] = 0.f;
    if (t < BK) deg[t] = 0.f;
    __syncthreads();

    const int start = boff[b], end = boff[b + 1];
    const int lane = t & 63;
    for (int idx = start + (t >> 6); idx < end; idx += 4) {
        const uint2 en = ent[idx];
        const unsigned partner = en.x;
        const unsigned edge  = en.y & 0x1FFFFFu;
        const unsigned local = en.y >> 21;
        const __hip_bfloat162 p = xh[(size_t)partner * 64 + lane];
        atomicAdd(&acc[local * 128 + 2 * lane],     __bfloat162float(p.x));
        atomicAdd(&acc[local * 128 + 2 * lane + 1], __bfloat162float(p.y));
        if (lane < 4)
            atomicAdd(&lab[local * 4 + lane], elabel[(size_t)edge * 4 + lane]);
        else if (lane == 4)
            atomicAdd(&deg[local], 1.f);
    }
    __syncthreads();
    if (t < BK) deg[t] = 1.f / fmaxf(deg[t], 1.f);
    __syncthreads();

    const int node0 = b * BK;
    for (int i = t; i < BK * 128; i += 256) {
        const int node = i >> 7;
        const int gn = node0 + node;
        if (gn < n) mean[(size_t)gn * 128 + (i & 127)] = acc[i] * deg[node];
    }
    for (int i = t; i < BK * 4; i += 256) {
        const int node = i >> 2;
        const int gn = node0 + node;
        if (gn < n) labmean[(size_t)gn * 4 + (i & 3)] = lab[i] * deg[node];
    }
}

// P1 = tw @ weight[128:256] (4x256), P3 = tw @ weight[384:512] (4x256)
__global__ void precompute_p(const float* __restrict__ tw, const float* __restrict__ weight,
                             float* __restrict__ P1, float* __restrict__ P3)
{
    const int o = threadIdx.x;
    #pragma unroll
    for (int l = 0; l < 4; ++l) {
        float s1 = 0.f, s3 = 0.f;
        for (int c = 0; c < 128; ++c) {
            const float t = tw[l * 128 + c];
            s1 = fmaf(t, weight[(size_t)(128 + c) * 256 + o], s1);
            s3 = fmaf(t, weight[(size_t)(384 + c) * 256 + o], s3);
        }
        P1[l * 256 + o] = s1;
        P3[l * 256 + o] = s3;
    }
}

// out[64 nodes x 256 cols] per block; K=256 main loop + rank-8 opinion epilogue
__global__ __launch_bounds__(256) void gemm_kernel(
    const float* __restrict__ out_mean, const float* __restrict__ inn_mean,
    const float* __restrict__ labr, const float* __restrict__ labc,
    const float* __restrict__ weight, const float* __restrict__ P1,
    const float* __restrict__ P3, const float* __restrict__ bias,
    float* __restrict__ out, int n_nodes)
{
    __shared__ float hs[64][33];
    __shared__ float ws[32][256];
    __shared__ float ps[8][256];
    __shared__ float labs[64][8];

    const int t = threadIdx.x;
    const int tx = t & 31;
    const int ty = t >> 5;
    const int node0 = blockIdx.x * 64;

    float acc[8][8];
    #pragma unroll
    for (int i = 0; i < 8; ++i)
        #pragma unroll
        for (int j = 0; j < 8; ++j) acc[i][j] = 0.f;

    for (int i = t; i < 2048; i += 256) {
        const int l = i >> 8, c = i & 255;
        ps[l][c] = (l < 4) ? P1[l * 256 + c] : P3[(l - 4) * 256 + c];
    }
    for (int i = t; i < 512; i += 256) {
        const int node = i >> 3, l = i & 7;
        const int gn = node0 + node;
        float v = 0.f;
        if (gn < n_nodes)
            v = (l < 4) ? labr[(size_t)gn * 4 + l] : labc[(size_t)gn * 4 + (l - 4)];
        labs[node][l] = v;
    }

    for (int kt = 0; kt < 8; ++kt) {
        const float* __restrict__ src = (kt < 4) ? out_mean : inn_mean;
        const int cbase = (kt & 3) * 32;
        const int wrow0 = (kt < 4) ? kt * 32 : 256 + (kt - 4) * 32;

        __syncthreads();

        {
            const int node = t >> 2;
            const int gn = node0 + node;
            const int kk0 = (t & 3) * 8;
            float4 a0 = make_float4(0.f, 0.f, 0.f, 0.f), a1 = a0;
            if (gn < n_nodes) {
                const float4* s4 = (const float4*)(src + (size_t)gn * 128 + cbase + kk0);
                a0 = s4[0]; a1 = s4[1];
            }
            hs[node][kk0 + 0] = a0.x;
            hs[node][kk0 + 1] = a0.y;
            hs[node][kk0 + 2] = a0.z;
            hs[node][kk0 + 3] = a0.w;
            hs[node][kk0 + 4] = a1.x;
            hs[node][kk0 + 5] = a1.y;
            hs[node][kk0 + 6] = a1.z;
            hs[node][kk0 + 7] = a1.w;
        }
        for (int kk = 0; kk < 32; ++kk)
            ws[kk][t] = weight[(size_t)(wrow0 + kk) * 256 + t];

        __syncthreads();

        for (int kk = 0; kk < 32; ++kk) {
            float a[8], bb[8];
            #pragma unroll
            for (int j = 0; j < 8; ++j) bb[j] = ws[kk][tx + 32 * j];
            #pragma unroll
            for (int i = 0; i < 8; ++i) a[i] = hs[ty * 8 + i][kk];
            #pragma unroll
            for (int i = 0; i < 8; ++i)
                #pragma unroll
                for (int j = 0; j < 8; ++j)
                    acc[i][j] = fmaf(a[i], bb[j], acc[i][j]);
        }
    }

    #pragma unroll
    for (int i = 0; i < 8; ++i) {
        const int node = ty * 8 + i;
        const int gn = node0 + node;
        if (gn >= n_nodes) continue;
        #pragma unroll
        for (int j = 0; j < 8; ++j) {
            const int oc = tx + 32 * j;
            float v = acc[i][j] + bias[oc];
            #pragma unroll
            for (int l = 0; l < 8; ++l) v = fmaf(labs[node][l], ps[l][oc], v);
            out[(size_t)gn * 256 + oc] = v;
        }
    }
}

extern "C" void kernel_launch(void* const* d_in, const int* in_sizes, int n_in,
                              void* d_out, int out_size, void* d_ws, size_t ws_size,
                              hipStream_t stream) {
    const float* x      = (const float*)d_in[0];
    const int*   eidx   = (const int*)d_in[1];
    const float* elabel = (const float*)d_in[2];
    const float* weight = (const float*)d_in[3];
    const float* tw     = (const float*)d_in[4];
    const float* bias   = (const float*)d_in[5];

    const int n = in_sizes[0] / 128;       // n_nodes
    const int E = in_sizes[2] / 4;         // n_edges
    const int nbk = (n + BK - 1) / BK;     // buckets (<=1024 for n<=131072)

    float* wf = (float*)d_ws;
    size_t o = 0;
    float* out_mean = wf + o; o += (size_t)n * 128;
    float* inn_mean = wf + o; o += (size_t)n * 128;
    float* labr     = wf + o; o += (size_t)n * 4;
    float* labc     = wf + o; o += (size_t)n * 4;
    float* P1       = wf + o; o += 1024;
    float* P3       = wf + o; o += 1024;
    int* wi = (int*)(wf + o);
    size_t oi = 0;
    int* cnt_r  = wi + oi; oi += nbk;      // memset to 0 each call
    int* cnt_c  = wi + oi; oi += nbk;
    int* boff_r = wi + oi; oi += nbk + 1;
    int* boff_c = wi + oi; oi += nbk + 1;
    int* cur_r  = wi + oi; oi += nbk;
    int* cur_c  = wi + oi; oi += nbk;

    // staged in d_out, fully consumed before gemm overwrites it
    uint2* ent_r = (uint2*)d_out;
    uint2* ent_c = ent_r + E;
    __hip_bfloat162* xh = (__hip_bfloat162*)(ent_c + E);

    hipMemsetAsync(cnt_r, 0, (size_t)2 * nbk * sizeof(int), stream);

    hipLaunchKernelGGL(convert_x, dim3(1024), dim3(256), 0, stream,
                       (const float2*)x, xh, n * 64);

    hipLaunchKernelGGL(precompute_p, dim3(1), dim3(256), 0, stream, tw, weight, P1, P3);

    hipLaunchKernelGGL(hist_b, dim3(512), dim3(256), 0, stream, eidx, cnt_r, cnt_c, E, nbk);

    hipLaunchKernelGGL(scan_b, dim3(2), dim3(1024), 0, stream,
                       cnt_r, cnt_c, boff_r, boff_c, cur_r, cur_c, nbk);

    hipLaunchKernelGGL(bin_kernel, dim3((E + 255) / 256), dim3(256), 0, stream,
                       eidx, cur_r, cur_c, ent_r, ent_c, E);

    hipLaunchKernelGGL(accum_b, dim3(nbk), dim3(256), 0, stream,
                       xh, elabel, ent_r, boff_r, out_mean, labr, n);
    hipLaunchKernelGGL(accum_b, dim3(nbk), dim3(256), 0, stream,
                       xh, elabel, ent_c, boff_c, inn_mean, labc, n);

    hipLaunchKernelGGL(gemm_kernel, dim3((n + 63) / 64), dim3(256), 0, stream,
                       out_mean, inn_mean, labr, labc, weight, P1, P3, bias,
                       (float*)d_out, n);
}

// Round 4
// 614.996 us; speedup vs baseline: 5.7763x; 5.7763x over previous
//
#include <hip/hip_runtime.h>
#include <hip/hip_bf16.h>

// x[N,128] f32, edge_index[2,E] int, edge_label[E,4] f32,
// weight[512,256] f32, trans_weight[4,128] f32, bias[256] f32 -> out[N,256] f32
//
// Pipeline:
//   convert_x : x -> bf16x2 (xh)
//   hist_b    : per-bucket (128 nodes) edge counts (LDS-preaggregated)
//   scan_b    : exclusive scan -> bucket offsets + global cursors
//   bin16     : two-pass per-block binning; 16B entries (partner|local, e, bf16 labels)
//               written in ~340B runs per bucket -> no write amplification
//   csrsort   : per-bucket exact per-node CSR (LDS hist+scan, scatter within 32KB window),
//               emits global rowptr
//   accum_csr : one wave per node, register accumulation, bf16 gathers, write mean once
//   gemm      : 64x256 tile, K=256 main loop + rank-8 opinion epilogue (P1/P3)

#define BK 128       // nodes per bucket
#define CHUNK 16384  // edges per bin16 block

__device__ inline unsigned pk_bf16(float a, float b) {
    __hip_bfloat162 h;
    h.x = __float2bfloat16(a);
    h.y = __float2bfloat16(b);
    return *reinterpret_cast<unsigned*>(&h);
}
__device__ inline float2 upk_bf16(unsigned u) {
    __hip_bfloat162 h = *reinterpret_cast<__hip_bfloat162*>(&u);
    return make_float2(__bfloat162float(h.x), __bfloat162float(h.y));
}

__global__ void convert_x(const float2* __restrict__ x2,
                          unsigned* __restrict__ xh, int n2)
{
    int i = blockIdx.x * 256 + threadIdx.x;
    const int stride = gridDim.x * 256;
    for (; i < n2; i += stride) {
        const float2 v = x2[i];
        xh[i] = pk_bf16(v.x, v.y);
    }
}

__global__ __launch_bounds__(256) void hist_b(const int* __restrict__ eidx,
                                              int* __restrict__ cnt_r,
                                              int* __restrict__ cnt_c, int E, int nbk)
{
    __shared__ int hr[1024], hc[1024];
    const int t = threadIdx.x;
    for (int i = t; i < nbk; i += 256) { hr[i] = 0; hc[i] = 0; }
    __syncthreads();
    for (int e = blockIdx.x * 256 + t; e < E; e += gridDim.x * 256) {
        atomicAdd(&hr[((unsigned)eidx[e]) >> 7], 1);
        atomicAdd(&hc[((unsigned)eidx[E + e]) >> 7], 1);
    }
    __syncthreads();
    for (int i = t; i < nbk; i += 256) {
        if (hr[i]) atomicAdd(&cnt_r[i], hr[i]);
        if (hc[i]) atomicAdd(&cnt_c[i], hc[i]);
    }
}

// blockIdx.x = 0 -> row, 1 -> col. nbk <= 1024.
__global__ __launch_bounds__(1024) void scan_b(const int* __restrict__ cnt_r,
                                               const int* __restrict__ cnt_c,
                                               int* __restrict__ boff_r,
                                               int* __restrict__ boff_c,
                                               int* __restrict__ cur_r,
                                               int* __restrict__ cur_c, int nbk)
{
    __shared__ int sh[1024];
    const int t = threadIdx.x;
    const int* cnt = blockIdx.x ? cnt_c : cnt_r;
    int* boff = blockIdx.x ? boff_c : boff_r;
    int* cur  = blockIdx.x ? cur_c  : cur_r;
    const int v = (t < nbk) ? cnt[t] : 0;
    sh[t] = v;
    __syncthreads();
    for (int s = 1; s < 1024; s <<= 1) {
        const int tmp = (t >= s) ? sh[t - s] : 0;
        __syncthreads();
        sh[t] += tmp;
        __syncthreads();
    }
    if (t < nbk) { const int off = sh[t] - v; boff[t] = off; cur[t] = off; }
    if (t == 0) boff[nbk] = sh[1023];
}

// Two-pass binning: count in LDS, reserve per bucket, scatter 16B entries in runs.
__global__ __launch_bounds__(256) void bin16(
    const int* __restrict__ eidx, const float4* __restrict__ elab4,
    int* __restrict__ cur_r, int* __restrict__ cur_c,
    uint4* __restrict__ ent_r, uint4* __restrict__ ent_c, int E, int nbk)
{
    __shared__ int cR[1024], cC[1024];
    const int t = threadIdx.x;
    const int base = blockIdx.x * CHUNK;
    for (int i = t; i < nbk; i += 256) { cR[i] = 0; cC[i] = 0; }
    __syncthreads();
    for (int k = t; k < CHUNK; k += 256) {
        const int e = base + k;
        if (e < E) {
            atomicAdd(&cR[((unsigned)eidx[e]) >> 7], 1);
            atomicAdd(&cC[((unsigned)eidx[E + e]) >> 7], 1);
        }
    }
    __syncthreads();
    for (int b = t; b < nbk; b += 256) {
        int c = cR[b]; cR[b] = c ? atomicAdd(&cur_r[b], c) : 0;
        c = cC[b];     cC[b] = c ? atomicAdd(&cur_c[b], c) : 0;
    }
    __syncthreads();
    for (int k = t; k < CHUNK; k += 256) {
        const int e = base + k;
        if (e < E) {
            const unsigned row = (unsigned)eidx[e];
            const unsigned col = (unsigned)eidx[E + e];
            const float4 lb = elab4[e];
            const unsigned l01 = pk_bf16(lb.x, lb.y);
            const unsigned l23 = pk_bf16(lb.z, lb.w);
            const int p = atomicAdd(&cR[row >> 7], 1);
            ent_r[p] = make_uint4(col | ((row & 127u) << 17), (unsigned)e, l01, l23);
            const int q = atomicAdd(&cC[col >> 7], 1);
            ent_c[q] = make_uint4(row | ((col & 127u) << 17), (unsigned)e, l01, l23);
        }
    }
}

// One block per bucket: exact per-node CSR within the bucket segment.
__global__ __launch_bounds__(256) void csrsort(
    const uint4* __restrict__ buf1, const int* __restrict__ boff,
    uint4* __restrict__ buf2, int* __restrict__ rptr, int n)
{
    __shared__ int hist[BK];
    __shared__ int sc[BK];
    __shared__ int curs[BK];
    const int t = threadIdx.x;
    const int b = blockIdx.x;
    const int s0 = boff[b], s1 = boff[b + 1];
    if (t < BK) hist[t] = 0;
    __syncthreads();
    for (int i = s0 + t; i < s1; i += 256)
        atomicAdd(&hist[buf1[i].x >> 17], 1);
    __syncthreads();
    if (t < BK) sc[t] = hist[t];
    __syncthreads();
    for (int s = 1; s < BK; s <<= 1) {
        int v = 0;
        if (t < BK && t >= s) v = sc[t - s];
        __syncthreads();
        if (t < BK) sc[t] += v;
        __syncthreads();
    }
    if (t < BK) {
        const int excl = sc[t] - hist[t];
        const int gn = b * BK + t;
        if (gn <= n) rptr[gn] = s0 + excl;
        curs[t] = s0 + excl;
    }
    __syncthreads();
    for (int i = s0 + t; i < s1; i += 256) {
        const uint4 en = buf1[i];
        const int p = atomicAdd(&curs[en.x >> 17], 1);
        buf2[p] = en;
    }
}

// One wave per node: register accumulation over its CSR segment, bf16 gathers.
__global__ __launch_bounds__(256) void accum_csr(
    const unsigned* __restrict__ xh, const uint4* __restrict__ ent,
    const int* __restrict__ rptr,
    float* __restrict__ mean, float* __restrict__ labmean, int n)
{
    const int lane = threadIdx.x;                  // 0..63
    const int node = blockIdx.x * 4 + threadIdx.y;
    if (node >= n) return;
    const int s = rptr[node];
    const int e = rptr[node + 1];
    float ax = 0.f, ay = 0.f, l0 = 0.f, l1 = 0.f, l2 = 0.f, l3 = 0.f;

    int i = s;
    for (; i + 3 < e; i += 4) {
        const uint4 e0 = ent[i], e1 = ent[i + 1], e2 = ent[i + 2], e3 = ent[i + 3];
        const unsigned g0 = xh[(size_t)(e0.x & 0x1FFFFu) * 64 + lane];
        const unsigned g1 = xh[(size_t)(e1.x & 0x1FFFFu) * 64 + lane];
        const unsigned g2 = xh[(size_t)(e2.x & 0x1FFFFu) * 64 + lane];
        const unsigned g3 = xh[(size_t)(e3.x & 0x1FFFFu) * 64 + lane];
        const float2 v0 = upk_bf16(g0), v1 = upk_bf16(g1),
                     v2 = upk_bf16(g2), v3 = upk_bf16(g3);
        ax += (v0.x + v1.x) + (v2.x + v3.x);
        ay += (v0.y + v1.y) + (v2.y + v3.y);
        const float2 a0 = upk_bf16(e0.z), b0 = upk_bf16(e0.w);
        const float2 a1 = upk_bf16(e1.z), b1 = upk_bf16(e1.w);
        const float2 a2 = upk_bf16(e2.z), b2 = upk_bf16(e2.w);
        const float2 a3 = upk_bf16(e3.z), b3 = upk_bf16(e3.w);
        l0 += (a0.x + a1.x) + (a2.x + a3.x);
        l1 += (a0.y + a1.y) + (a2.y + a3.y);
        l2 += (b0.x + b1.x) + (b2.x + b3.x);
        l3 += (b0.y + b1.y) + (b2.y + b3.y);
    }
    for (; i < e; ++i) {
        const uint4 e0 = ent[i];
        const unsigned g0 = xh[(size_t)(e0.x & 0x1FFFFu) * 64 + lane];
        const float2 v0 = upk_bf16(g0);
        ax += v0.x; ay += v0.y;
        const float2 a0 = upk_bf16(e0.z), b0 = upk_bf16(e0.w);
        l0 += a0.x; l1 += a0.y; l2 += b0.x; l3 += b0.y;
    }

    const float inv = 1.0f / fmaxf((float)(e - s), 1.0f);
    ((float2*)mean)[(size_t)node * 64 + lane] = make_float2(ax * inv, ay * inv);
    if (lane < 4) {
        const float lv = (lane == 0) ? l0 : (lane == 1) ? l1 : (lane == 2) ? l2 : l3;
        labmean[(size_t)node * 4 + lane] = lv * inv;
    }
}

// P1 = tw @ weight[128:256] (4x256), P3 = tw @ weight[384:512] (4x256)
__global__ void precompute_p(const float* __restrict__ tw, const float* __restrict__ weight,
                             float* __restrict__ P1, float* __restrict__ P3)
{
    const int o = threadIdx.x;
    #pragma unroll
    for (int l = 0; l < 4; ++l) {
        float s1 = 0.f, s3 = 0.f;
        for (int c = 0; c < 128; ++c) {
            const float t = tw[l * 128 + c];
            s1 = fmaf(t, weight[(size_t)(128 + c) * 256 + o], s1);
            s3 = fmaf(t, weight[(size_t)(384 + c) * 256 + o], s3);
        }
        P1[l * 256 + o] = s1;
        P3[l * 256 + o] = s3;
    }
}

// out[64 nodes x 256 cols] per block; K=256 main loop + rank-8 opinion epilogue
__global__ __launch_bounds__(256) void gemm_kernel(
    const float* __restrict__ out_mean, const float* __restrict__ inn_mean,
    const float* __restrict__ labr, const float* __restrict__ labc,
    const float* __restrict__ weight, const float* __restrict__ P1,
    const float* __restrict__ P3, const float* __restrict__ bias,
    float* __restrict__ out, int n_nodes)
{
    __shared__ float hs[64][33];
    __shared__ float ws[32][256];
    __shared__ float ps[8][256];
    __shared__ float labs[64][8];

    const int t = threadIdx.x;
    const int tx = t & 31;
    const int ty = t >> 5;
    const int node0 = blockIdx.x * 64;

    float acc[8][8];
    #pragma unroll
    for (int i = 0; i < 8; ++i)
        #pragma unroll
        for (int j = 0; j < 8; ++j) acc[i][j] = 0.f;

    for (int i = t; i < 2048; i += 256) {
        const int l = i >> 8, c = i & 255;
        ps[l][c] = (l < 4) ? P1[l * 256 + c] : P3[(l - 4) * 256 + c];
    }
    for (int i = t; i < 512; i += 256) {
        const int node = i >> 3, l = i & 7;
        const int gn = node0 + node;
        float v = 0.f;
        if (gn < n_nodes)
            v = (l < 4) ? labr[(size_t)gn * 4 + l] : labc[(size_t)gn * 4 + (l - 4)];
        labs[node][l] = v;
    }

    for (int kt = 0; kt < 8; ++kt) {
        const float* __restrict__ src = (kt < 4) ? out_mean : inn_mean;
        const int cbase = (kt & 3) * 32;
        const int wrow0 = (kt < 4) ? kt * 32 : 256 + (kt - 4) * 32;

        __syncthreads();

        {
            const int node = t >> 2;
            const int gn = node0 + node;
            const int kk0 = (t & 3) * 8;
            float4 a0 = make_float4(0.f, 0.f, 0.f, 0.f), a1 = a0;
            if (gn < n_nodes) {
                const float4* s4 = (const float4*)(src + (size_t)gn * 128 + cbase + kk0);
                a0 = s4[0]; a1 = s4[1];
            }
            hs[node][kk0 + 0] = a0.x;
            hs[node][kk0 + 1] = a0.y;
            hs[node][kk0 + 2] = a0.z;
            hs[node][kk0 + 3] = a0.w;
            hs[node][kk0 + 4] = a1.x;
            hs[node][kk0 + 5] = a1.y;
            hs[node][kk0 + 6] = a1.z;
            hs[node][kk0 + 7] = a1.w;
        }
        for (int kk = 0; kk < 32; ++kk)
            ws[kk][t] = weight[(size_t)(wrow0 + kk) * 256 + t];

        __syncthreads();

        for (int kk = 0; kk < 32; ++kk) {
            float a[8], bb[8];
            #pragma unroll
            for (int j = 0; j < 8; ++j) bb[j] = ws[kk][tx + 32 * j];
            #pragma unroll
            for (int i = 0; i < 8; ++i) a[i] = hs[ty * 8 + i][kk];
            #pragma unroll
            for (int i = 0; i < 8; ++i)
                #pragma unroll
                for (int j = 0; j < 8; ++j)
                    acc[i][j] = fmaf(a[i], bb[j], acc[i][j]);
        }
    }

    #pragma unroll
    for (int i = 0; i < 8; ++i) {
        const int node = ty * 8 + i;
        const int gn = node0 + node;
        if (gn >= n_nodes) continue;
        #pragma unroll
        for (int j = 0; j < 8; ++j) {
            const int oc = tx + 32 * j;
            float v = acc[i][j] + bias[oc];
            #pragma unroll
            for (int l = 0; l < 8; ++l) v = fmaf(labs[node][l], ps[l][oc], v);
            out[(size_t)gn * 256 + oc] = v;
        }
    }
}

extern "C" void kernel_launch(void* const* d_in, const int* in_sizes, int n_in,
                              void* d_out, int out_size, void* d_ws, size_t ws_size,
                              hipStream_t stream) {
    const float* x      = (const float*)d_in[0];
    const int*   eidx   = (const int*)d_in[1];
    const float* elabel = (const float*)d_in[2];
    const float* weight = (const float*)d_in[3];
    const float* tw     = (const float*)d_in[4];
    const float* bias   = (const float*)d_in[5];

    const int n = in_sizes[0] / 128;       // n_nodes (100000, < 2^17)
    const int E = in_sizes[2] / 4;         // n_edges (1.6M, < 2^21)
    const int nbk = (n + BK - 1) / BK;     // buckets (<=1024)

    // ---- workspace layout (floats) ----
    float* wf = (float*)d_ws;
    float* out_mean = wf;
    float* inn_mean = wf + (size_t)n * 128;
    uint4* ent2_r   = (uint4*)inn_mean;    // alias: consumed by accum_r before accum_c writes inn_mean
    float* labr     = wf + (size_t)2 * n * 128;
    float* labc     = labr + (size_t)n * 4;
    float* P1       = labc + (size_t)n * 4;
    float* P3       = P1 + 1024;
    int* rptr_r = (int*)(P3 + 1024);
    int* rptr_c = rptr_r + (n + 1);
    int* cnt_r  = rptr_c + (n + 1);
    int* cnt_c  = cnt_r + nbk;
    int* boff_r = cnt_c + nbk;
    int* boff_c = boff_r + (nbk + 1);
    int* cur_r  = boff_c + (nbk + 1);
    int* cur_c  = cur_r + nbk;

    // ---- d_out staging (exactly out_size*4 = 102.4 MB) ----
    char* ob = (char*)d_out;
    unsigned* xh  = (unsigned*)ob;                       // n*64 u32 = 25.6 MB
    uint4* ent1_r = (uint4*)(ob + (size_t)n * 256);      // E*16 = 25.6 MB
    uint4* ent1_c = ent1_r + E;                          // 25.6 MB
    uint4* ent2_c = ent1_c + E;                          // 25.6 MB

    hipMemsetAsync(cnt_r, 0, (size_t)2 * nbk * sizeof(int), stream);

    hipLaunchKernelGGL(convert_x, dim3(1024), dim3(256), 0, stream,
                       (const float2*)x, xh, n * 64);

    hipLaunchKernelGGL(precompute_p, dim3(1), dim3(256), 0, stream, tw, weight, P1, P3);

    hipLaunchKernelGGL(hist_b, dim3(512), dim3(256), 0, stream, eidx, cnt_r, cnt_c, E, nbk);

    hipLaunchKernelGGL(scan_b, dim3(2), dim3(1024), 0, stream,
                       cnt_r, cnt_c, boff_r, boff_c, cur_r, cur_c, nbk);

    hipLaunchKernelGGL(bin16, dim3((E + CHUNK - 1) / CHUNK), dim3(256), 0, stream,
                       eidx, (const float4*)elabel, cur_r, cur_c, ent1_r, ent1_c, E, nbk);

    hipLaunchKernelGGL(csrsort, dim3(nbk), dim3(256), 0, stream,
                       ent1_r, boff_r, ent2_r, rptr_r, n);
    hipLaunchKernelGGL(csrsort, dim3(nbk), dim3(256), 0, stream,
                       ent1_c, boff_c, ent2_c, rptr_c, n);

    dim3 ablock(64, 4);
    hipLaunchKernelGGL(accum_csr, dim3((n + 3) / 4), ablock, 0, stream,
                       xh, ent2_r, rptr_r, out_mean, labr, n);
    hipLaunchKernelGGL(accum_csr, dim3((n + 3) / 4), ablock, 0, stream,
                       xh, ent2_c, rptr_c, inn_mean, labc, n);

    hipLaunchKernelGGL(gemm_kernel, dim3((n + 63) / 64), dim3(256), 0, stream,
                       out_mean, inn_mean, labr, labc, weight, P1, P3, bias,
                       (float*)d_out, n);
}

// Round 5
// 431.502 us; speedup vs baseline: 8.2327x; 1.4252x over previous
//
#include <hip/hip_runtime.h>
#include <hip/hip_bf16.h>

// x[N,128] f32, edge_index[2,E] int, edge_label[E,4] f32,
// weight[512,256] f32, trans_weight[4,128] f32, bias[256] f32 -> out[N,256] f32
//
// Pipeline:
//   convert_x : x -> bf16x2 (xh, in d_out)
//   precompute_p / prep_wb : fold opinion GEMM into P1/P3; pack B (K=288 eff) into
//               MFMA fragment layout (bf16), 144 KB L2-resident
//   hist_b/scan_b/bin16 : bucket (128-node) binning, 8B entries
//               (partner|local<<17, labels as u8x4)
//   csrsort   : per-bucket exact per-node CSR within 16KB window, emits rowptr
//   accum_u8  : one wave per node, register accumulation, bf16 gathers,
//               integer label sums, writes bf16 means once
//   gemm_mfma : 64x256 tile, 4 waves, mfma_f32_16x16x32_bf16, K=288
//               (main 256 + rank-8 labels + pad), bias epilogue

#define BK 128
#define CHUNK 16384
#define LDA 296   // bf16 units per LDS row (288 + 8 pad -> 592B = 148 dwords, 2-way max)

typedef unsigned short u16;
typedef __attribute__((ext_vector_type(4))) float f32x4;
typedef __attribute__((ext_vector_type(8))) short bf16x8;

__device__ inline unsigned pk_bf16(float a, float b) {
    __hip_bfloat162 h;
    h.x = __float2bfloat16(a);
    h.y = __float2bfloat16(b);
    return *reinterpret_cast<unsigned*>(&h);
}
__device__ inline float2 upk_bf16(unsigned u) {
    __hip_bfloat162 h = *reinterpret_cast<__hip_bfloat162*>(&u);
    return make_float2(__bfloat162float(h.x), __bfloat162float(h.y));
}
__device__ inline u16 f2bf(float f) {
    __hip_bfloat16 h = __float2bfloat16(f);
    return *reinterpret_cast<u16*>(&h);
}

__global__ void convert_x(const float2* __restrict__ x2,
                          unsigned* __restrict__ xh, int n2)
{
    int i = blockIdx.x * 256 + threadIdx.x;
    const int stride = gridDim.x * 256;
    for (; i < n2; i += stride) {
        const float2 v = x2[i];
        xh[i] = pk_bf16(v.x, v.y);
    }
}

// P1 = tw @ weight[128:256] (4x256), P3 = tw @ weight[384:512] (4x256)
__global__ void precompute_p(const float* __restrict__ tw, const float* __restrict__ weight,
                             float* __restrict__ P1, float* __restrict__ P3)
{
    const int o = threadIdx.x;
    #pragma unroll
    for (int l = 0; l < 4; ++l) {
        float s1 = 0.f, s3 = 0.f;
        for (int c = 0; c < 128; ++c) {
            const float t = tw[l * 128 + c];
            s1 = fmaf(t, weight[(size_t)(128 + c) * 256 + o], s1);
            s3 = fmaf(t, weight[(size_t)(384 + c) * 256 + o], s3);
        }
        P1[l * 256 + o] = s1;
        P3[l * 256 + o] = s3;
    }
}

// Pack effective B [288 x 256] into per-fragment layout:
// wb[((ks*16+ct)*64 + lane)*8 + j] = B_eff[ks*32 + (lane>>4)*8 + j][ct*16 + (lane&15)]
// B_eff rows: [0:128)=W[0:128], [128:256)=W[256:384], [256:260)=P1, [260:264)=P3, rest 0.
__global__ __launch_bounds__(256) void prep_wb(const float* __restrict__ w,
                                               const float* __restrict__ P1f,
                                               const float* __restrict__ P3f,
                                               u16* __restrict__ wb)
{
    const int pid = blockIdx.x * 256 + threadIdx.x;   // 0..9215
    if (pid >= 9 * 16 * 64) return;
    const int ks = pid >> 10;
    const int ct = (pid >> 6) & 15;
    const int l  = pid & 63;
    const int col = ct * 16 + (l & 15);
    const int k0 = ks * 32 + ((l >> 4) << 3);
    u16 v[8];
    #pragma unroll
    for (int j = 0; j < 8; ++j) {
        const int k = k0 + j;
        float f = 0.f;
        if (k < 128)      f = w[(size_t)k * 256 + col];
        else if (k < 256) f = w[(size_t)(k + 128) * 256 + col];
        else if (k < 260) f = P1f[(k - 256) * 256 + col];
        else if (k < 264) f = P3f[(k - 260) * 256 + col];
        v[j] = f2bf(f);
    }
    *(uint4*)(wb + (size_t)pid * 8) = *(uint4*)v;
}

__global__ __launch_bounds__(256) void hist_b(const int* __restrict__ eidx,
                                              int* __restrict__ cnt_r,
                                              int* __restrict__ cnt_c, int E, int nbk)
{
    __shared__ int hr[1024], hc[1024];
    const int t = threadIdx.x;
    for (int i = t; i < nbk; i += 256) { hr[i] = 0; hc[i] = 0; }
    __syncthreads();
    for (int e = blockIdx.x * 256 + t; e < E; e += gridDim.x * 256) {
        atomicAdd(&hr[((unsigned)eidx[e]) >> 7], 1);
        atomicAdd(&hc[((unsigned)eidx[E + e]) >> 7], 1);
    }
    __syncthreads();
    for (int i = t; i < nbk; i += 256) {
        if (hr[i]) atomicAdd(&cnt_r[i], hr[i]);
        if (hc[i]) atomicAdd(&cnt_c[i], hc[i]);
    }
}

__global__ __launch_bounds__(1024) void scan_b(const int* __restrict__ cnt_r,
                                               const int* __restrict__ cnt_c,
                                               int* __restrict__ boff_r,
                                               int* __restrict__ boff_c,
                                               int* __restrict__ cur_r,
                                               int* __restrict__ cur_c, int nbk)
{
    __shared__ int sh[1024];
    const int t = threadIdx.x;
    const int* cnt = blockIdx.x ? cnt_c : cnt_r;
    int* boff = blockIdx.x ? boff_c : boff_r;
    int* cur  = blockIdx.x ? cur_c  : cur_r;
    const int v = (t < nbk) ? cnt[t] : 0;
    sh[t] = v;
    __syncthreads();
    for (int s = 1; s < 1024; s <<= 1) {
        const int tmp = (t >= s) ? sh[t - s] : 0;
        __syncthreads();
        sh[t] += tmp;
        __syncthreads();
    }
    if (t < nbk) { const int off = sh[t] - v; boff[t] = off; cur[t] = off; }
    if (t == 0) boff[nbk] = sh[1023];
}

// Two-pass binning: count in LDS, reserve per bucket, scatter 8B entries in runs.
__global__ __launch_bounds__(256) void bin16(
    const int* __restrict__ eidx, const float4* __restrict__ elab4,
    int* __restrict__ cur_r, int* __restrict__ cur_c,
    uint2* __restrict__ ent_r, uint2* __restrict__ ent_c, int E, int nbk)
{
    __shared__ int cR[1024], cC[1024];
    const int t = threadIdx.x;
    const int base = blockIdx.x * CHUNK;
    for (int i = t; i < nbk; i += 256) { cR[i] = 0; cC[i] = 0; }
    __syncthreads();
    for (int k = t; k < CHUNK; k += 256) {
        const int e = base + k;
        if (e < E) {
            atomicAdd(&cR[((unsigned)eidx[e]) >> 7], 1);
            atomicAdd(&cC[((unsigned)eidx[E + e]) >> 7], 1);
        }
    }
    __syncthreads();
    for (int b = t; b < nbk; b += 256) {
        int c = cR[b]; cR[b] = c ? atomicAdd(&cur_r[b], c) : 0;
        c = cC[b];     cC[b] = c ? atomicAdd(&cur_c[b], c) : 0;
    }
    __syncthreads();
    for (int k = t; k < CHUNK; k += 256) {
        const int e = base + k;
        if (e < E) {
            const unsigned row = (unsigned)eidx[e];
            const unsigned col = (unsigned)eidx[E + e];
            const float4 lb = elab4[e];
            const unsigned q0 = (unsigned)(lb.x * 255.f + 0.5f);
            const unsigned q1 = (unsigned)(lb.y * 255.f + 0.5f);
            const unsigned q2 = (unsigned)(lb.z * 255.f + 0.5f);
            const unsigned q3 = (unsigned)(lb.w * 255.f + 0.5f);
            const unsigned lq = q0 | (q1 << 8) | (q2 << 16) | (q3 << 24);
            const int p = atomicAdd(&cR[row >> 7], 1);
            ent_r[p] = make_uint2(col | ((row & 127u) << 17), lq);
            const int q = atomicAdd(&cC[col >> 7], 1);
            ent_c[q] = make_uint2(row | ((col & 127u) << 17), lq);
        }
    }
}

// One block per bucket: exact per-node CSR within the bucket segment.
__global__ __launch_bounds__(256) void csrsort(
    const uint2* __restrict__ buf1, const int* __restrict__ boff,
    uint2* __restrict__ buf2, int* __restrict__ rptr, int nn)
{
    __shared__ int hist[BK];
    __shared__ int sc[BK];
    __shared__ int curs[BK];
    const int t = threadIdx.x;
    const int b = blockIdx.x;
    const int s0 = boff[b], s1 = boff[b + 1];
    if (t < BK) hist[t] = 0;
    __syncthreads();
    for (int i = s0 + t; i < s1; i += 256)
        atomicAdd(&hist[buf1[i].x >> 17], 1);
    __syncthreads();
    if (t < BK) sc[t] = hist[t];
    __syncthreads();
    for (int s = 1; s < BK; s <<= 1) {
        int v = 0;
        if (t < BK && t >= s) v = sc[t - s];
        __syncthreads();
        if (t < BK) sc[t] += v;
        __syncthreads();
    }
    if (t < BK) {
        const int excl = sc[t] - hist[t];
        const int gn = b * BK + t;
        if (gn <= nn) rptr[gn] = s0 + excl;
        curs[t] = s0 + excl;
    }
    __syncthreads();
    for (int i = s0 + t; i < s1; i += 256) {
        const uint2 en = buf1[i];
        const int p = atomicAdd(&curs[en.x >> 17], 1);
        buf2[p] = en;
    }
}

// One wave per node: register accumulation, bf16 gathers, u8 label integer sums.
__global__ __launch_bounds__(256) void accum_u8(
    const unsigned* __restrict__ xh, const uint2* __restrict__ ent,
    const int* __restrict__ rptr, unsigned* __restrict__ mean_h,
    u16* __restrict__ labm_h, int nn)
{
    const int lane = threadIdx.x;                  // 0..63
    const int node = blockIdx.x * 4 + threadIdx.y;
    if (node >= nn) return;
    const int s = rptr[node];
    const int e = rptr[node + 1];
    float ax = 0.f, ay = 0.f;
    unsigned labq = 0;
    const unsigned sh = (lane & 3) * 8;

    int i = s;
    for (; i + 3 < e; i += 4) {
        const uint2 e0 = ent[i], e1 = ent[i + 1], e2 = ent[i + 2], e3 = ent[i + 3];
        const unsigned g0 = xh[(size_t)(e0.x & 0x1FFFFu) * 64 + lane];
        const unsigned g1 = xh[(size_t)(e1.x & 0x1FFFFu) * 64 + lane];
        const unsigned g2 = xh[(size_t)(e2.x & 0x1FFFFu) * 64 + lane];
        const unsigned g3 = xh[(size_t)(e3.x & 0x1FFFFu) * 64 + lane];
        const float2 v0 = upk_bf16(g0), v1 = upk_bf16(g1),
                     v2 = upk_bf16(g2), v3 = upk_bf16(g3);
        ax += (v0.x + v1.x) + (v2.x + v3.x);
        ay += (v0.y + v1.y) + (v2.y + v3.y);
        if (lane < 4)
            labq += ((e0.y >> sh) & 255u) + ((e1.y >> sh) & 255u)
                  + ((e2.y >> sh) & 255u) + ((e3.y >> sh) & 255u);
    }
    for (; i < e; ++i) {
        const uint2 e0 = ent[i];
        const float2 v0 = upk_bf16(xh[(size_t)(e0.x & 0x1FFFFu) * 64 + lane]);
        ax += v0.x; ay += v0.y;
        if (lane < 4) labq += (e0.y >> sh) & 255u;
    }

    const float inv = 1.0f / fmaxf((float)(e - s), 1.0f);
    mean_h[(size_t)node * 64 + lane] = pk_bf16(ax * inv, ay * inv);
    if (lane < 4)
        labm_h[(size_t)node * 4 + lane] = f2bf((float)labq * inv * (1.f / 255.f));
}

// MFMA GEMM: out[64 x 256] per block, K=288 (256 means + 8 labels + 24 pad).
__global__ __launch_bounds__(256) void gemm_mfma(
    const u16* __restrict__ om_h, const u16* __restrict__ im_h,
    const u16* __restrict__ labr_h, const u16* __restrict__ labc_h,
    const u16* __restrict__ wb, const float* __restrict__ bias,
    float* __restrict__ out, int nn)
{
    __shared__ u16 hA[64 * LDA];
    const int t = threadIdx.x;
    const int w = t >> 6;
    const int lane = t & 63;
    const int node0 = blockIdx.x * 64;

    // stage A: 64 rows x 288 bf16 (36 chunks of 8), zero-pad cols 264..287
    for (int idx = t; idx < 2304; idx += 256) {
        const int row = idx / 36;
        const int c8 = idx - row * 36;
        const int gn = node0 + row;
        uint4 val = make_uint4(0, 0, 0, 0);
        if (gn < nn) {
            if (c8 < 16)
                val = *(const uint4*)(om_h + (size_t)gn * 128 + c8 * 8);
            else if (c8 < 32)
                val = *(const uint4*)(im_h + (size_t)gn * 128 + (c8 - 16) * 8);
            else if (c8 == 32) {
                const uint2 a = *(const uint2*)(labr_h + (size_t)gn * 4);
                const uint2 b = *(const uint2*)(labc_h + (size_t)gn * 4);
                val = make_uint4(a.x, a.y, b.x, b.y);
            }
        }
        *(uint4*)(&hA[row * LDA + c8 * 8]) = val;
    }
    __syncthreads();

    f32x4 acc[4][4];
    #pragma unroll
    for (int i = 0; i < 4; ++i)
        #pragma unroll
        for (int j = 0; j < 4; ++j)
            acc[i][j] = (f32x4){0.f, 0.f, 0.f, 0.f};

    const int m15 = lane & 15;
    const int kq  = lane >> 4;

    for (int ks = 0; ks < 9; ++ks) {
        const int koff = ks * 32 + kq * 8;
        bf16x8 af[4], bfr[4];
        #pragma unroll
        for (int nt = 0; nt < 4; ++nt)
            af[nt] = *(const bf16x8*)(&hA[(nt * 16 + m15) * LDA + koff]);
        #pragma unroll
        for (int c2 = 0; c2 < 4; ++c2)
            bfr[c2] = *(const bf16x8*)(wb + ((size_t)((ks * 16 + w * 4 + c2) * 64 + lane)) * 8);
        #pragma unroll
        for (int nt = 0; nt < 4; ++nt)
            #pragma unroll
            for (int c2 = 0; c2 < 4; ++c2)
                acc[nt][c2] = __builtin_amdgcn_mfma_f32_16x16x32_bf16(
                    af[nt], bfr[c2], acc[nt][c2], 0, 0, 0);
    }

    #pragma unroll
    for (int nt = 0; nt < 4; ++nt) {
        const int gnb = node0 + nt * 16 + kq * 4;
        #pragma unroll
        for (int c2 = 0; c2 < 4; ++c2) {
            const int oc = w * 64 + c2 * 16 + m15;
            const float bv = bias[oc];
            #pragma unroll
            for (int r = 0; r < 4; ++r) {
                const int gn = gnb + r;
                if (gn < nn) out[(size_t)gn * 256 + oc] = acc[nt][c2][r] + bv;
            }
        }
    }
}

extern "C" void kernel_launch(void* const* d_in, const int* in_sizes, int n_in,
                              void* d_out, int out_size, void* d_ws, size_t ws_size,
                              hipStream_t stream) {
    const float* x      = (const float*)d_in[0];
    const int*   eidx   = (const int*)d_in[1];
    const float* elabel = (const float*)d_in[2];
    const float* weight = (const float*)d_in[3];
    const float* tw     = (const float*)d_in[4];
    const float* bias   = (const float*)d_in[5];

    const int n = in_sizes[0] / 128;       // n_nodes (100000 < 2^17)
    const int E = in_sizes[2] / 4;         // n_edges (1.6M)
    const int nbk = (n + BK - 1) / BK;     // buckets (<=1024)

    // ---- workspace layout (bytes) ----
    char* wsb = (char*)d_ws;
    u16* om_h   = (u16*)wsb;                      wsb += (size_t)n * 128 * 2;
    u16* im_h   = (u16*)wsb;                      wsb += (size_t)n * 128 * 2;
    u16* labr_h = (u16*)wsb;                      wsb += (size_t)n * 4 * 2;
    u16* labc_h = (u16*)wsb;                      wsb += (size_t)n * 4 * 2;
    float* P1f  = (float*)wsb;                    wsb += 1024 * 4;
    float* P3f  = (float*)wsb;                    wsb += 1024 * 4;
    u16* wb     = (u16*)wsb;                      wsb += 9216 * 8 * 2;
    int* rptr_r = (int*)wsb;                      wsb += (size_t)(n + 1) * 4;
    int* rptr_c = (int*)wsb;                      wsb += (size_t)(n + 1) * 4;
    int* cnt_r  = (int*)wsb;                      wsb += nbk * 4;
    int* cnt_c  = (int*)wsb;                      wsb += nbk * 4;
    int* boff_r = (int*)wsb;                      wsb += (nbk + 1) * 4;
    int* boff_c = (int*)wsb;                      wsb += (nbk + 1) * 4;
    int* cur_r  = (int*)wsb;                      wsb += nbk * 4;
    int* cur_c  = (int*)wsb;                      wsb += nbk * 4;

    // ---- d_out staging (76.8 MB of 102.4 MB), all consumed before gemm ----
    unsigned* xh = (unsigned*)d_out;              // n*64 u32 = 25.6 MB
    uint2* ent1_r = (uint2*)(xh + (size_t)n * 64);
    uint2* ent1_c = ent1_r + E;
    uint2* ent2_r = ent1_c + E;
    uint2* ent2_c = ent2_r + E;

    hipMemsetAsync(cnt_r, 0, (size_t)2 * nbk * sizeof(int), stream);

    hipLaunchKernelGGL(convert_x, dim3(1024), dim3(256), 0, stream,
                       (const float2*)x, xh, n * 64);

    hipLaunchKernelGGL(precompute_p, dim3(1), dim3(256), 0, stream, tw, weight, P1f, P3f);
    hipLaunchKernelGGL(prep_wb, dim3(36), dim3(256), 0, stream, weight, P1f, P3f, wb);

    hipLaunchKernelGGL(hist_b, dim3(512), dim3(256), 0, stream, eidx, cnt_r, cnt_c, E, nbk);

    hipLaunchKernelGGL(scan_b, dim3(2), dim3(1024), 0, stream,
                       cnt_r, cnt_c, boff_r, boff_c, cur_r, cur_c, nbk);

    hipLaunchKernelGGL(bin16, dim3((E + CHUNK - 1) / CHUNK), dim3(256), 0, stream,
                       eidx, (const float4*)elabel, cur_r, cur_c, ent1_r, ent1_c, E, nbk);

    hipLaunchKernelGGL(csrsort, dim3(nbk), dim3(256), 0, stream,
                       ent1_r, boff_r, ent2_r, rptr_r, n);
    hipLaunchKernelGGL(csrsort, dim3(nbk), dim3(256), 0, stream,
                       ent1_c, boff_c, ent2_c, rptr_c, n);

    dim3 ablock(64, 4);
    hipLaunchKernelGGL(accum_u8, dim3((n + 3) / 4), ablock, 0, stream,
                       xh, ent2_r, rptr_r, (unsigned*)om_h, labr_h, n);
    hipLaunchKernelGGL(accum_u8, dim3((n + 3) / 4), ablock, 0, stream,
                       xh, ent2_c, rptr_c, (unsigned*)im_h, labc_h, n);

    hipLaunchKernelGGL(gemm_mfma, dim3((n + 63) / 64), dim3(256), 0, stream,
                       om_h, im_h, labr_h, labc_h, wb, bias, (float*)d_out, n);
}